// Round 7
// baseline (1264.951 us; speedup 1.0000x reference)
//
#include <hip/hip_runtime.h>

static constexpr int MM  = 90000;  // cells
static constexpr int TT  = 150;    // steps
static constexpr int BS  = 256;    // threads per block (4 waves)
static constexpr int CPT = 11;     // cells per thread
static constexpr int CPB2 = BS * CPT;              // 2816 cells per block
static constexpr int NB2  = 32;                    // sim blocks (fit ONE XCD: 32 CUs)
static constexpr int WPB  = BS / 64;               // 4 waves
static constexpr int NLAUNCH = 512;                // candidates; losers exit fast
static constexpr int PG32 = 512;                   // 2KB bmax page per slot
static constexpr int PG64 = 1024;                  // 8KB edge page per slot
static constexpr int GUARD_MAX = 8192;             // spin cap -> fast-fail, not hang
static constexpr int FLAGW = NB2 * PG32;           // 16384 u32
static constexpr int TOTW  = FLAGW + NB2 * PG64 * 2;  // + edge as u32 = 81920

typedef unsigned int u32x2 __attribute__((ext_vector_type(2)));

// Flag state. All flags are per-step slots, never reused => value-is-flag is
// MONOTONE within a launch (0 -> final). Cross-launch staleness is killed by
// init_ws zeroing from EVERY XCD (plain stores update any stale dirty L2 line
// in place; sc1 stores zero the IF copy). Stale==0 is always SAFE (retry).
__device__ __attribute__((aligned(128))) unsigned int       g_bmax[NB2][PG32]; // [slot][t]
__device__ __attribute__((aligned(128))) unsigned long long g_edge[NB2][PG64]; // [slot][t*4+side*2+{AQ,F}]
__device__ int          g_cnt[8];     // per-XCD block counters (device atomics)
__device__ unsigned int g_winner;     // rep+1 of the XCD that seated 32 blocks first

__device__ __forceinline__ float softplus_f(float x) {
    return fmaxf(x, 0.0f) + log1pf(expf(-fabsf(x)));
}
__device__ __forceinline__ unsigned long long packAQ(float A, float Q) {
    return ((unsigned long long)__float_as_uint(Q) << 32) | (unsigned long long)__float_as_uint(A);
}

// Dual-publish: plain store (updates/dirties the local L2 line -> local atomic
// readers see it fast) + sc1 store (IF copy -> sc1 fallback readers see it).
#define DSTORE32(p, v) asm volatile("global_store_dword %0, %1, off\n\t"            \
                                    "global_store_dword %0, %1, off sc1"            \
                                    :: "v"(p), "v"(v) : "memory")
#define DSTORE64(p, v) asm volatile("global_store_dwordx2 %0, %1, off\n\t"          \
                                    "global_store_dwordx2 %0, %1, off sc1"          \
                                    :: "v"(p), "v"(v) : "memory")
// sc1 fused loads (R1-proven): liveness net, reads the IF copy.
#define SLD32(d, p) asm volatile("global_load_dword %0, %1, off sc1\n\t"            \
                                 "s_waitcnt vmcnt(0)" : "=&v"(d) : "v"(p) : "memory")
#define SLD64(d, p) asm volatile("global_load_dwordx2 %0, %1, off sc1\n\t"          \
                                 "s_waitcnt vmcnt(0)" : "=&v"(d) : "v"(p) : "memory")
#define SC1_LD32(d, p) asm volatile("global_load_dword %0, %1, off sc1\n\ts_waitcnt vmcnt(0)" \
                                    : "=v"(d) : "v"(p) : "memory")
// Local poll primitive: atomic RMW executes AT the L2 (cannot see stale L1). R6-proven.
#define LOC_ADD32(p, z) __hip_atomic_fetch_add((unsigned int*)(p), (z), \
                            __ATOMIC_RELAXED, __HIP_MEMORY_SCOPE_WORKGROUP)
#define LOC_ADD64(p, z) __hip_atomic_fetch_add((unsigned long long*)(p), (z), \
                            __ATOMIC_RELAXED, __HIP_MEMORY_SCOPE_WORKGROUP)
#define FENCE_LDS() asm volatile("s_waitcnt lgkmcnt(0)" ::: "memory")
// Raw barrier: lgkmcnt-only. Skips __syncthreads' vmcnt(0) drain, so sc1
// flag-store acks never sit on the barrier critical path (R1's hidden ~500cy tax).
#define BAR() do { asm volatile("s_waitcnt lgkmcnt(0)" ::: "memory");               \
                   __builtin_amdgcn_s_barrier();                                    \
                   __builtin_amdgcn_sched_barrier(0); } while (0)

// 64-lane max reduce in 6 DPP stages; lane 63 ends with the full max. Values >= 0.
#define DPP_MAX(x, ctrl, rm, bm)                                                \
    x = fmaxf(x, __int_as_float(__builtin_amdgcn_update_dpp(                    \
                     0, __float_as_int(x), (ctrl), (rm), (bm), true)))
__device__ __forceinline__ float wave_max64(float x) {
    DPP_MAX(x, 0x111, 0xf, 0xf);   // row_shr:1
    DPP_MAX(x, 0x112, 0xf, 0xf);   // row_shr:2
    DPP_MAX(x, 0x114, 0xf, 0xe);   // row_shr:4
    DPP_MAX(x, 0x118, 0xf, 0xc);   // row_shr:8
    DPP_MAX(x, 0x142, 0xa, 0xf);   // row_bcast:15
    DPP_MAX(x, 0x143, 0xc, 0xf);   // row_bcast:31 -> lane 63 = full max
    return x;
}

__global__ void init_ws_kernel() {
    const int bid = blockIdx.x, tid = threadIdx.x;
    if (bid == 0 && tid < 9) {
        if (tid < 8) atomicExch(&g_cnt[tid], 0);
        else         atomicExch(&g_winner, 0u);
    }
    // Every block zeroes 1/8 of the flag region with plain+sc1 stores. Chunk id
    // (bid>>3)&7 decorrelates from the (likely bid%8) XCD mapping, so each XCD's
    // resident init blocks cover all 8 chunks -> stale dirty lines from the
    // previous launch get updated to 0 IN PLACE in every L2.
    unsigned int* pb = &g_bmax[0][0];
    unsigned int* pe = (unsigned int*)&g_edge[0][0];
    const int chunk = (bid >> 3) & 7;
    const int lo = chunk * (TOTW / 8), hi = lo + (TOTW / 8);
    for (int j = lo + tid; j < hi; j += BS) {
        unsigned int* p = (j < FLAGW) ? (pb + j) : (pe + (j - FLAGW));
        asm volatile("global_store_dword %0, %1, off"     :: "v"(p), "v"(0u) : "memory");
        asm volatile("global_store_dword %0, %1, off sc1" :: "v"(p), "v"(0u) : "memory");
    }
}

__global__ void __launch_bounds__(BS, 1) sim_kernel(
    const float* __restrict__ Rs,
    const float* __restrict__ sim_dat,
    const float* __restrict__ sdc,
    const float* __restrict__ inflow,
    float* __restrict__ out)
{
    __shared__ float sE[2][WPB][2][3];     // [parity][wave][L/R edge cell][A,Q,F]
    __shared__ float s_redf[TT + 1][WPB];  // per-step per-wave max value-flags
    __shared__ float s_inflow[TT];
    __shared__ float s_bc[2][2];           // [parity][lam,w]
    __shared__ float s_hL[2][3], s_hR[2][3];  // [parity][A,Q,F] remote halo
    __shared__ int   s_panic;
    __shared__ int   s_slot, s_go;

    const int tid  = threadIdx.x;
    const int wv   = tid >> 6;
    const int lane = tid & 63;

    // ===== election: the first XCD to seat 32 blocks runs the sim alone =====
    if (tid == 0) {
        unsigned int xcc;
        asm volatile("s_getreg_b32 %0, hwreg(HW_REG_XCC_ID)" : "=s"(xcc));
        const int rep = (int)(xcc & 7u);
        const int slot = atomicAdd(&g_cnt[rep], 1);
        if (slot == NB2 - 1) atomicCAS(&g_winner, 0u, (unsigned)(rep + 1));
        unsigned int w;
        for (;;) { SC1_LD32(w, &g_winner); if (w != 0u) break; __builtin_amdgcn_s_sleep(32); }
        s_slot = slot;
        s_go   = (slot < NB2) && ((unsigned)(rep + 1) == w);
    }
    __syncthreads();
    if (!s_go) return;
    const int slot = s_slot;

    for (int j = tid; j < TT; j += BS) s_inflow[j] = inflow[j];
    for (int j = tid; j < (TT + 1) * WPB; j += BS) (&s_redf[0][0])[j] = 0.0f;
    if (tid == 0) s_panic = 0;
    __syncthreads();   // full barrier once, pre-loop

    // opaque zero: defeats idempotent-RMW -> load lowering (would re-create R5's L1 bug)
    unsigned int zo_;
    asm volatile("v_mov_b32 %0, 0" : "=v"(zo_));
    const unsigned int       zo   = zo_;
    const unsigned long long zo64 = zo_;

    const int base = slot * CPB2 + tid * CPT;   // 11 contiguous cells per thread

    // ---- per-cell constants & initial state (registers all sim) ----
    float A[CPT], Q[CPT], A0v[CPT], bet[CPT], cbv[CPT], k2v[CPT], sq[CPT], FQ[CPT];
    bool  act[CPT];
    #pragma unroll
    for (int c = 0; c < CPT; ++c) {
        int i = base + c;
        act[c] = (i < MM);
        if (act[c]) {
            A[c]   = fmaxf(sim_dat[i], 1e-6f);
            Q[c]   = 0.1f * sim_dat[MM + i];
            A0v[c] = sdc[i] + 0.5f;
            bet[c] = sdc[MM + i] + 1.0f;
        } else { A[c] = 1.0f; Q[c] = 0.0f; A0v[c] = 1.0f; bet[c] = 1.0f; }
        cbv[c] = (0.5f * bet[c]) / 1060.0f;     // (0.5*beta)/RHO  (ref op order)
        k2v[c] = bet[c] / (3180.0f * A0v[c]);   // beta/(3*RHO*A0)
    }
    // per-cell special roles (vessel bounds no longer thread-aligned at CPT=11)
    int startC = -1, endC = -1, midC = -1, midSlot = -1;
    #pragma unroll
    for (int c = 0; c < CPT; ++c) {
        int i = base + c;
        if (i == 0 || i == 30000 || i == 60000) startC = c;
        if (i == 29999 || i == 59999 || i == 89999) endC = c;
        if (i == 15000) { midC = c; midSlot = 0; }
        else if (i == 45000) { midC = c; midSlot = 1; }
        else if (i == 75000) { midC = c; midSlot = 2; }
    }
    float Rtot = 1.0f;
    if (endC >= 0) {
        int i3 = base + endC;
        float R1 = sdc[7 * MM + i3] + 0.5f;
        float R2 = sdc[8 * MM + i3] + 0.5f;
        if (i3 == 59999)      { R1 *= softplus_f(Rs[0]); R2 *= softplus_f(Rs[1]); }
        else if (i3 == 89999) { R1 *= softplus_f(Rs[2]); R2 *= softplus_f(Rs[3]); }
        Rtot = R1 + R2;
    }

    const bool pubL = (tid == 0) && (slot > 0);
    const bool pubR = (tid == BS - 1) && (slot < NB2 - 1);

    // ---- initial derived state + t=0 publishes ----
    float s4 = 0.0f;
    #pragma unroll
    for (int c = 0; c < CPT; ++c) {
        sq[c] = sqrtf(A[c] / A0v[c]);
        float uu = Q[c] / A[c];
        float cc = sqrtf(cbv[c] * sq[c]);
        FQ[c] = Q[c] * uu + k2v[c] * A[c] * sq[c];
        s4 = fmaxf(s4, act[c] ? (fabsf(uu) + cc) : 0.0f);
    }
    if (pubL) { unsigned long long v = packAQ(A[0], Q[0]);
                u32x2 e0 = { (unsigned int)v, (unsigned int)(v >> 32) };
                u32x2 e1 = { __float_as_uint(FQ[0]), 0u };
                DSTORE64(&g_edge[slot][0], e0); DSTORE64(&g_edge[slot][1], e1); }
    if (pubR) { unsigned long long v = packAQ(A[CPT-1], Q[CPT-1]);
                u32x2 e0 = { (unsigned int)v, (unsigned int)(v >> 32) };
                u32x2 e1 = { __float_as_uint(FQ[CPT-1]), 0u };
                DSTORE64(&g_edge[slot][2], e0); DSTORE64(&g_edge[slot][3], e1); }
    if (lane == 0)       { sE[0][wv][0][0] = A[0];      sE[0][wv][0][1] = Q[0];      sE[0][wv][0][2] = FQ[0]; }
    else if (lane == 63) { sE[0][wv][1][0] = A[CPT-1];  sE[0][wv][1][1] = Q[CPT-1];  sE[0][wv][1][2] = FQ[CPT-1]; }
    {
        float red = wave_max64(s4);
        FENCE_LDS();
        if (lane == 63) {
            if (wv > 0) s_redf[0][wv] = red;
            else {
                volatile float* sf = &s_redf[0][0];
                int g2 = 0; float r1, r2, r3;
                do { r1 = sf[1]; r2 = sf[2]; r3 = sf[3]; ++g2; }
                while ((r1 == 0.0f || r2 == 0.0f || r3 == 0.0f) && g2 < GUARD_MAX);
                float bm = fmaxf(fmaxf(red, r1), fmaxf(r2, r3));
                DSTORE32(&g_bmax[slot][0], __float_as_uint(bm));
            }
        }
    }

    for (int t = 0; t < TT; ++t) {
        const int par = t & 1, npar = par ^ 1;

        // ===== overlap phase (all waves): register-only neighbor exchange =====
        float Am = __shfl_up(A[CPT-1], 1, 64),  Qm = __shfl_up(Q[CPT-1], 1, 64),  Fm = __shfl_up(FQ[CPT-1], 1, 64);
        float Ap = __shfl_down(A[0], 1, 64),    Qp = __shfl_down(Q[0], 1, 64),    Fp = __shfl_down(FQ[0], 1, 64);

        float dFA[CPT], lapA[CPT], dFQ[CPT], lapQ[CPT];
        #pragma unroll
        for (int c = 0; c < CPT; ++c) {
            float Al = (c == 0) ? Am : A[c-1],      Ql = (c == 0) ? Qm : Q[c-1],      Fl = (c == 0) ? Fm : FQ[c-1];
            float Ar = (c == CPT-1) ? Ap : A[c+1],  Qr = (c == CPT-1) ? Qp : Q[c+1],  Fr = (c == CPT-1) ? Fp : FQ[c+1];
            dFA[c]  = 0.5f * (Qr - Ql);
            lapA[c] = 0.5f * (Ar - 2.0f * A[c] + Al);
            dFQ[c]  = 0.5f * (Fr - Fl);
            lapQ[c] = 0.5f * (Qr - 2.0f * Q[c] + Ql);
        }
        if (midC >= 0) out[t * 3 + midSlot] = bet[midC] * (sq[midC] - 1.0f);
        float qStart = 0.0f, qEnd = 0.0f;
        if (startC >= 0) qStart = s_inflow[t];
        if (endC   >= 0) qEnd   = (bet[endC] * (sq[endC] - 1.0f)) / Rtot;

        // ===== wave0: L2-local flat poll (atomics) + every-4th sc1 liveness net =====
        if (wv == 0) {
            const int t4 = t * 4;
            const bool hasA = (lane < NB2);
            const unsigned int* pA = &g_bmax[lane & (NB2 - 1)][t];
            const unsigned long long* pC = nullptr;
            bool hasC = false;
            if (lane == 32 && slot > 0)             { hasC = true; pC = &g_edge[slot - 1][t4 + 2]; }
            else if (lane == 33 && slot > 0)        { hasC = true; pC = &g_edge[slot - 1][t4 + 3]; }
            else if (lane == 34 && slot < NB2 - 1)  { hasC = true; pC = &g_edge[slot + 1][t4 + 0]; }
            else if (lane == 35 && slot < NB2 - 1)  { hasC = true; pC = &g_edge[slot + 1][t4 + 1]; }

            unsigned int ra = 1u;
            unsigned long long rc = ~0ull;
            int it = 0, guard = 0;
            for (;;) {
                if ((++it & 3) != 0) {                   // local rounds: L2 atomic RMW
                    if (hasA) ra = LOC_ADD32(pA, zo);
                    if (hasC) rc = LOC_ADD64(pC, zo64);
                } else {                                  // liveness net: IF copy via sc1
                    if (hasA) SLD32(ra, pA);
                    if (hasC) { u32x2 tmp; SLD64(tmp, pC);
                                rc = ((unsigned long long)tmp.y << 32) | tmp.x; }
                }
                bool ok = ((!hasA) | (ra != 0u)) & ((!hasC) | ((unsigned int)rc != 0u));
                if (__all(ok)) break;
                if (++guard >= GUARD_MAX) break;
            }
            // halo hand-off (parity slot) before the barrier
            if (lane == 32 && slot > 0)            { s_hL[par][0] = __uint_as_float((unsigned int)rc);
                                                     s_hL[par][1] = __uint_as_float((unsigned int)(rc >> 32)); }
            else if (lane == 33 && slot > 0)       { s_hL[par][2] = __uint_as_float((unsigned int)rc); }
            else if (lane == 34 && slot < NB2 - 1) { s_hR[par][0] = __uint_as_float((unsigned int)rc);
                                                     s_hR[par][1] = __uint_as_float((unsigned int)(rc >> 32)); }
            else if (lane == 35 && slot < NB2 - 1) { s_hR[par][2] = __uint_as_float((unsigned int)rc); }
            float v = hasA ? __uint_as_float(ra) : 0.0f;
            float m = wave_max64(v);
            const float smax = __int_as_float(__builtin_amdgcn_readlane(__float_as_int(m), 63));
            const float dt  = ((float)(0.9 * 0.001)) / smax;   // ref op order
            const float lam = dt / 0.001f;
            const float w   = lam * smax;
            if (lane == 0) {
                s_bc[par][0] = lam; s_bc[par][1] = w;
                if (guard >= GUARD_MAX) s_panic = 1;
            }
        }
        BAR();   // raw barrier: lgkmcnt-only, no vmcnt drain
        if (s_panic) break;
        const float lam = s_bc[par][0];
        const float w   = s_bc[par][1];

        // ===== per-wave edge fixes =====
        if (lane == 0 && (wv > 0 || slot > 0)) {
            float Al, Ql, Fl;
            if (wv > 0) { Al = sE[par][wv-1][1][0]; Ql = sE[par][wv-1][1][1]; Fl = sE[par][wv-1][1][2]; }
            else        { Al = s_hL[par][0];        Ql = s_hL[par][1];        Fl = s_hL[par][2]; }
            dFA[0]  = 0.5f * (Q[1] - Ql);
            lapA[0] = 0.5f * (A[1] - 2.0f * A[0] + Al);
            dFQ[0]  = 0.5f * (FQ[1] - Fl);
            lapQ[0] = 0.5f * (Q[1] - 2.0f * Q[0] + Ql);
        }
        if (lane == 63 && (wv < WPB - 1 || slot < NB2 - 1)) {
            float Ar, Qr, Fr;
            if (wv < WPB - 1) { Ar = sE[par][wv+1][0][0]; Qr = sE[par][wv+1][0][1]; Fr = sE[par][wv+1][0][2]; }
            else              { Ar = s_hR[par][0];        Qr = s_hR[par][1];        Fr = s_hR[par][2]; }
            dFA[CPT-1]  = 0.5f * (Qr - Q[CPT-2]);
            lapA[CPT-1] = 0.5f * (Ar - 2.0f * A[CPT-1] + A[CPT-2]);
            dFQ[CPT-1]  = 0.5f * (Qr - FQ[CPT-2]) * 0.0f + 0.5f * (Fr - FQ[CPT-2]);   // dFQ uses F
            lapQ[CPT-1] = 0.5f * (Qr - 2.0f * Q[CPT-1] + Q[CPT-2]);
        }

        // ===== update + BCs + clamp =====
        #pragma unroll
        for (int c = 0; c < CPT; ++c) {
            int i = base + c;
            if (act[c] && i > 0 && i < MM - 1) {
                A[c] = fmaf(w, lapA[c], fmaf(-lam, dFA[c], A[c]));
                Q[c] = fmaf(w, lapQ[c], fmaf(-lam, dFQ[c], Q[c]));
            }
        }
        if (startC >= 0) Q[startC] = qStart;
        if (endC   >= 0) Q[endC]   = qEnd;
        #pragma unroll
        for (int c = 0; c < CPT; ++c) A[c] = fmaxf(A[c], 1e-6f);

        // publish t+1 edge AQ ASAP (raw barrier => these sc1 acks never stall anyone)
        const int n4 = (t + 1) * 4;
        if (pubL) { unsigned long long v = packAQ(A[0], Q[0]);
                    u32x2 e0 = { (unsigned int)v, (unsigned int)(v >> 32) };
                    DSTORE64(&g_edge[slot][n4 + 0], e0); }
        if (pubR) { unsigned long long v = packAQ(A[CPT-1], Q[CPT-1]);
                    u32x2 e0 = { (unsigned int)v, (unsigned int)(v >> 32) };
                    DSTORE64(&g_edge[slot][n4 + 2], e0); }

        // ===== derived state for t+1 =====
        s4 = 0.0f;
        #pragma unroll
        for (int c = 0; c < CPT; ++c) {
            sq[c] = sqrtf(A[c] / A0v[c]);
            float uu = Q[c] / A[c];
            float cc = sqrtf(cbv[c] * sq[c]);
            FQ[c] = Q[c] * uu + k2v[c] * A[c] * sq[c];
            s4 = fmaxf(s4, act[c] ? (fabsf(uu) + cc) : 0.0f);
        }
        if (pubL) { u32x2 e1 = { __float_as_uint(FQ[0]), 0u };
                    DSTORE64(&g_edge[slot][n4 + 1], e1); }
        if (pubR) { u32x2 e1 = { __float_as_uint(FQ[CPT-1]), 0u };
                    DSTORE64(&g_edge[slot][n4 + 3], e1); }

        // intra-block wave-edge state + per-wave flag + block-max publish
        if (lane == 0)       { sE[npar][wv][0][0] = A[0];      sE[npar][wv][0][1] = Q[0];      sE[npar][wv][0][2] = FQ[0]; }
        else if (lane == 63) { sE[npar][wv][1][0] = A[CPT-1];  sE[npar][wv][1][1] = Q[CPT-1];  sE[npar][wv][1][2] = FQ[CPT-1]; }
        {
            float red = wave_max64(s4);
            FENCE_LDS();   // sE + anything LDS lands before the flag others spin on
            if (lane == 63) {
                if (wv > 0) s_redf[t + 1][wv] = red;       // LDS value-flag (fresh slot)
                else {
                    volatile float* sf = &s_redf[t + 1][0];
                    int g2 = 0; float r1, r2, r3;
                    do { r1 = sf[1]; r2 = sf[2]; r3 = sf[3]; ++g2; }
                    while ((r1 == 0.0f || r2 == 0.0f || r3 == 0.0f) && g2 < GUARD_MAX);
                    float bm = fmaxf(fmaxf(red, r1), fmaxf(r2, r3));
                    DSTORE32(&g_bmax[slot][t + 1], __float_as_uint(bm));
                }
            }
        }
    }
}

extern "C" void kernel_launch(void* const* d_in, const int* in_sizes, int n_in,
                              void* d_out, int out_size, void* d_ws, size_t ws_size,
                              hipStream_t stream) {
    (void)in_sizes; (void)n_in; (void)d_ws; (void)ws_size; (void)out_size;

    const float* Rs      = (const float*)d_in[0];
    const float* sim_dat = (const float*)d_in[1];
    const float* sdc     = (const float*)d_in[2];
    const float* inflow  = (const float*)d_in[3];
    float* out = (float*)d_out;

    hipLaunchKernelGGL(init_ws_kernel, dim3(NLAUNCH), dim3(BS), 0, stream);

    // 512 candidate blocks; the first XCD to seat 32 wins and runs the whole sim
    // on its own L2. Losers exit in microseconds. launch_bounds(256,1): 1 block/CU
    // guaranteed resident at any VGPR count -> every XCD seats >=32 candidates.
    hipLaunchKernelGGL(sim_kernel, dim3(NLAUNCH), dim3(BS), 0, stream,
                       Rs, sim_dat, sdc, inflow, out);
}

// Round 8
// 464.070 us; speedup vs baseline: 2.7258x; 2.7258x over previous
//
#include <hip/hip_runtime.h>

static constexpr int MM  = 90000;  // cells
static constexpr int TT  = 150;    // steps
static constexpr int BS  = 256;    // threads per block (4 waves)
static constexpr int CPT = 4;      // cells per thread
static constexpr int CPB = BS * CPT;               // 1024 cells per block
static constexpr int NB  = (MM + CPB - 1) / CPB;   // 88 blocks
static constexpr int WPB = BS / 64;                // 4 waves per block
static constexpr int NWAVE = NB * WPB;             // 352 waves
static constexpr int WPAGES = 384;                 // 64 lanes x 6 loads (352 real + 32 sentinel)
static constexpr int PAGE_U32 = 2048;              // 8 KB page -> own channel
static constexpr int PAGE_U64 = 1024;              // 8 KB page per block (halo words)
static constexpr int GUARD_MAX = 4096;             // spin cap -> fast wrong answer, never hang

typedef unsigned int u32x2 __attribute__((ext_vector_type(2)));

// Persistent device globals, re-initialized by init_ws_kernel EVERY launch.
// g_wmax[gw][t]: wave gw's |u|+c max at step t (nonzero by construction, c>=6e-4).
// One writer per 8KB page. Pages >= NWAVE preset to 1u (sentinels, fmax-neutral).
__device__ __attribute__((aligned(128))) unsigned int       g_wmax[WPAGES][PAGE_U32];
__device__ __attribute__((aligned(128))) unsigned long long g_edge_s[NB][PAGE_U64]; // [b][t*4+side*2+{AQ,F}]
__device__ unsigned long long g_dummy64;                    // always nonzero (boundary filler)

__device__ __forceinline__ float softplus_f(float x) {
    return fmaxf(x, 0.0f) + log1pf(expf(-fabsf(x)));
}
__device__ __forceinline__ unsigned long long packAQ(float A, float Q) {
    return ((unsigned long long)__float_as_uint(Q) << 32) | (unsigned long long)__float_as_uint(A);
}
#define AG_STORE32(p, v) __hip_atomic_store((p), (v), __ATOMIC_RELAXED, __HIP_MEMORY_SCOPE_AGENT)
#define AG_STORE64(p, v) __hip_atomic_store((p), (v), __ATOMIC_RELAXED, __HIP_MEMORY_SCOPE_AGENT)

// One poll sample = 6 wmax dwords + 1 halo dwordx2, issued with NO waitcnt.
#define ISSUE7(x0,x1,x2,x3,x4,x5,e,p0,p1,p2,p3,p4,p5,pe)                        \
    asm volatile("global_load_dword %0, %7, off sc1\n\t"                        \
                 "global_load_dword %1, %8, off sc1\n\t"                        \
                 "global_load_dword %2, %9, off sc1\n\t"                        \
                 "global_load_dword %3, %10, off sc1\n\t"                       \
                 "global_load_dword %4, %11, off sc1\n\t"                       \
                 "global_load_dword %5, %12, off sc1\n\t"                       \
                 "global_load_dwordx2 %6, %13, off sc1"                         \
                 : "=&v"(x0),"=&v"(x1),"=&v"(x2),"=&v"(x3),"=&v"(x4),"=&v"(x5),"=&v"(e) \
                 : "v"(p0),"v"(p1),"v"(p2),"v"(p3),"v"(p4),"v"(p5),"v"(pe)      \
                 : "memory")
// Counted wait that TIES the polled values through the asm ("+v"): the nonzero
// check's SSA inputs are DEFINED by this asm, so the compiler cannot hoist the
// check above the wait (rule-#18 defense, stronger than sched_barrier alone).
#define WAIT7_TIE(x0,x1,x2,x3,x4,x5,e)                                          \
    do { asm volatile("s_waitcnt vmcnt(7)"                                      \
             : "+v"(x0),"+v"(x1),"+v"(x2),"+v"(x3),"+v"(x4),"+v"(x5),"+v"(e)    \
             :: "memory");                                                      \
         __builtin_amdgcn_sched_barrier(0); } while (0)
#define CHK7(x0,x1,x2,x3,x4,x5,e)                                               \
    __all(((x0) != 0u) & ((x1) != 0u) & ((x2) != 0u) & ((x3) != 0u) &           \
          ((x4) != 0u) & ((x5) != 0u) & ((e).x != 0u))
#define FENCE_LDS() asm volatile("s_waitcnt lgkmcnt(0)" ::: "memory")
// Raw barrier: lgkmcnt-only (no vmcnt drain -> sc1 publish acks never stall it).
#define BAR() do { FENCE_LDS();                                                 \
                   __builtin_amdgcn_s_barrier();                                \
                   __builtin_amdgcn_sched_barrier(0); } while (0)

// 64-lane max reduce in 6 DPP stages; lane 63 ends with the full max. Values >= 0.
#define DPP_MAX(x, ctrl, rm, bm)                                                \
    x = fmaxf(x, __int_as_float(__builtin_amdgcn_update_dpp(                    \
                     0, __float_as_int(x), (ctrl), (rm), (bm), true)))
__device__ __forceinline__ float wave_max64(float x) {
    DPP_MAX(x, 0x111, 0xf, 0xf);   // row_shr:1
    DPP_MAX(x, 0x112, 0xf, 0xf);   // row_shr:2
    DPP_MAX(x, 0x114, 0xf, 0xe);   // row_shr:4
    DPP_MAX(x, 0x118, 0xf, 0xc);   // row_shr:8
    DPP_MAX(x, 0x142, 0xa, 0xf);   // row_bcast:15
    DPP_MAX(x, 0x143, 0xc, 0xf);   // row_bcast:31 -> lane 63 = full max
    return x;
}

__global__ void init_ws_kernel() {
    int i = blockIdx.x * blockDim.x + threadIdx.x;
    int stride = gridDim.x * blockDim.x;
    unsigned int* pw = &g_wmax[0][0];
    for (int j = i; j < WPAGES * PAGE_U32; j += stride)
        pw[j] = ((j >> 11) < NWAVE) ? 0u : 1u;   // sentinel pages "already arrived"
    unsigned long long* pe = &g_edge_s[0][0];
    for (int j = i; j < NB * PAGE_U64; j += stride) pe[j] = 0ull;
    if (i == 0) g_dummy64 = ~0ull;
}

__global__ void __launch_bounds__(BS) sim_kernel(
    const float* __restrict__ Rs,
    const float* __restrict__ sim_dat,
    const float* __restrict__ sdc,
    const float* __restrict__ inflow,
    float* __restrict__ out)
{
    __shared__ float sE[2][WPB][2][3];   // [parity][wave][L/R edge cell][A,Q,F] (state_t)
    __shared__ float s_smaxv;            // final smax (ordered by the raw barrier)
    __shared__ float s_hL[3], s_hR[3];   // remote halo (A,Q,F)
    __shared__ float s_inflow[TT];
    __shared__ int   s_panic;

    const int b    = blockIdx.x;
    const int tid  = threadIdx.x;
    const int wv   = tid >> 6;
    const int lane = tid & 63;
    const int base = b * CPB + tid * CPT;   // 4 contiguous cells per thread
    const int gw   = b * WPB + wv;          // global wave id -> own wmax page

    for (int j = tid; j < TT; j += BS) s_inflow[j] = inflow[j];
    if (tid == 0) s_panic = 0;

    // ---- per-cell constants & initial state (registers all sim) ----
    float A[CPT], Q[CPT], A0v[CPT], bet[CPT], cbv[CPT], k2v[CPT], sq[CPT], FQ[CPT];
    bool  act[CPT];
    #pragma unroll
    for (int c = 0; c < CPT; ++c) {
        int i = base + c;
        act[c] = (i < MM);
        if (act[c]) {
            A[c]   = fmaxf(sim_dat[i], 1e-6f);
            Q[c]   = 0.1f * sim_dat[MM + i];
            A0v[c] = sdc[i] + 0.5f;
            bet[c] = sdc[MM + i] + 1.0f;
        } else { A[c] = 1.0f; Q[c] = 0.0f; A0v[c] = 1.0f; bet[c] = 1.0f; }
        cbv[c] = (0.5f * bet[c]) / 1060.0f;     // (0.5*beta)/RHO  (ref op order)
        k2v[c] = bet[c] / (3180.0f * A0v[c]);   // beta/(3*RHO*A0)
    }
    const bool isStart = (base == 0) | (base == 30000) | (base == 60000);                  // cell 0
    const bool isEnd   = (base + 3 == 29999) | (base + 3 == 59999) | (base + 3 == 89999);  // cell 3
    const int midSlot = (base == 15000) ? 0 : (base == 45000) ? 1 : (base == 75000) ? 2 : -1;
    float Rtot = 1.0f;
    if (isEnd) {
        int i3 = base + 3;
        float R1 = sdc[7 * MM + i3] + 0.5f;
        float R2 = sdc[8 * MM + i3] + 0.5f;
        if (i3 == 59999)      { R1 *= softplus_f(Rs[0]); R2 *= softplus_f(Rs[1]); }
        else if (i3 == 89999) { R1 *= softplus_f(Rs[2]); R2 *= softplus_f(Rs[3]); }
        Rtot = R1 + R2;
    }

    const bool pubL = (tid == 0) && (b > 0);            // publish my left edge (read by b-1)
    const bool pubR = (tid == BS - 1) && (b < NB - 1);  // publish my right edge (read by b+1)

    // ---- initial derived state + t=0 publishes ----
    float s4 = 0.0f;
    #pragma unroll
    for (int c = 0; c < CPT; ++c) {
        sq[c] = sqrtf(A[c] / A0v[c]);
        float uu = Q[c] / A[c];
        float cc = sqrtf(cbv[c] * sq[c]);
        FQ[c] = Q[c] * uu + k2v[c] * A[c] * sq[c];
        s4 = fmaxf(s4, act[c] ? (fabsf(uu) + cc) : 0.0f);
    }
    if (pubL) {   // my L-edge words: [b][t*4+0]=AQ, [b][t*4+1]=F
        AG_STORE64(&g_edge_s[b][0], packAQ(A[0], Q[0]));
        AG_STORE64(&g_edge_s[b][1], (unsigned long long)__float_as_uint(FQ[0]));
    }
    if (pubR) {   // my R-edge words: [b][t*4+2]=AQ, [b][t*4+3]=F
        AG_STORE64(&g_edge_s[b][2], packAQ(A[3], Q[3]));
        AG_STORE64(&g_edge_s[b][3], (unsigned long long)__float_as_uint(FQ[3]));
    }
    {
        float red = wave_max64(s4);
        if (lane == 63) AG_STORE32(&g_wmax[gw][0], __float_as_uint(red));
    }
    if (lane == 0)       { sE[0][wv][0][0] = A[0]; sE[0][wv][0][1] = Q[0]; sE[0][wv][0][2] = FQ[0]; }
    else if (lane == 63) { sE[0][wv][1][0] = A[3]; sE[0][wv][1][1] = Q[3]; sE[0][wv][1][2] = FQ[3]; }
    // no pre-loop barrier needed: first in-loop BAR() orders sE/s_inflow/s_panic.

    for (int t = 0; t < TT; ++t) {
        const int par = t & 1, npar = par ^ 1;

        // ===== wave0: issue poll sample B (NON-blocking, hidden under overlap) =====
        unsigned int b0, b1, b2, b3, b4, b5, c0, c1, c2, c3, c4, c5;
        u32x2 bE, cE;
        const unsigned int *p0, *p1, *p2, *p3, *p4, *p5;
        const unsigned long long* pE;
        if (wv == 0) {
            p0 = &g_wmax[lane      ][t];  p1 = &g_wmax[lane +  64][t];
            p2 = &g_wmax[lane + 128][t];  p3 = &g_wmax[lane + 192][t];
            p4 = &g_wmax[lane + 256][t];  p5 = &g_wmax[lane + 320][t];
            const int t4 = t * 4;
            pE = &g_dummy64;
            if (lane == 0 && b > 0)           pE = &g_edge_s[b - 1][t4 + 2];  // left nbr R-AQ
            else if (lane == 1 && b > 0)      pE = &g_edge_s[b - 1][t4 + 3];  // left nbr R-F
            else if (lane == 2 && b < NB - 1) pE = &g_edge_s[b + 1][t4 + 0];  // right nbr L-AQ
            else if (lane == 3 && b < NB - 1) pE = &g_edge_s[b + 1][t4 + 1];  // right nbr L-F
            ISSUE7(b0, b1, b2, b3, b4, b5, bE, p0, p1, p2, p3, p4, p5, pE);
        }

        // ===== overlap phase (all waves): register-only neighbor exchange =====
        float Am = __shfl_up(A[3], 1, 64),  Qm = __shfl_up(Q[3], 1, 64),  Fm = __shfl_up(FQ[3], 1, 64);
        float Ap = __shfl_down(A[0], 1, 64), Qp = __shfl_down(Q[0], 1, 64), Fp = __shfl_down(FQ[0], 1, 64);

        float dFA[CPT], lapA[CPT], dFQ[CPT], lapQ[CPT];
        #pragma unroll
        for (int c = 0; c < CPT; ++c) {
            float Al = (c == 0) ? Am : A[c-1],  Ql = (c == 0) ? Qm : Q[c-1],  Fl = (c == 0) ? Fm : FQ[c-1];
            float Ar = (c == 3) ? Ap : A[c+1],  Qr = (c == 3) ? Qp : Q[c+1],  Fr = (c == 3) ? Fp : FQ[c+1];
            dFA[c]  = 0.5f * (Qr - Ql);
            lapA[c] = 0.5f * (Ar - 2.0f * A[c] + Al);
            dFQ[c]  = 0.5f * (Fr - Fl);
            lapQ[c] = 0.5f * (Qr - 2.0f * Q[c] + Ql);
        }
        if (midSlot >= 0) out[t * 3 + midSlot] = bet[0] * (sq[0] - 1.0f);
        // BC values depend only on step-t state: compute (incl. divide) pre-spin
        float qFix = 0.0f;
        if (isStart) qFix = s_inflow[t];
        if (isEnd)   qFix = (bet[3] * (sq[3] - 1.0f)) / Rtot;

        // ===== wave0: 2-deep pipelined poll (deterministic period ~RT/2) =====
        if (wv == 0) {
            ISSUE7(c0, c1, c2, c3, c4, c5, cE, p0, p1, p2, p3, p4, p5, pE);
            WAIT7_TIE(b0, b1, b2, b3, b4, b5, bE);        // B landed (C in flight)
            if (!CHK7(b0, b1, b2, b3, b4, b5, bE)) {
                int guard = 0;
                for (;;) {
                    ISSUE7(b0, b1, b2, b3, b4, b5, bE, p0, p1, p2, p3, p4, p5, pE);
                    WAIT7_TIE(c0, c1, c2, c3, c4, c5, cE);    // C landed (B in flight)
                    if (CHK7(c0, c1, c2, c3, c4, c5, cE)) {
                        b0=c0; b1=c1; b2=c2; b3=c3; b4=c4; b5=c5; bE=cE; break;
                    }
                    ISSUE7(c0, c1, c2, c3, c4, c5, cE, p0, p1, p2, p3, p4, p5, pE);
                    WAIT7_TIE(b0, b1, b2, b3, b4, b5, bE);    // B landed (C in flight)
                    if (CHK7(b0, b1, b2, b3, b4, b5, bE)) break;
                    if (++guard >= GUARD_MAX) { if (lane == 0) s_panic = 1; break; }
                }
                // exit leaves one stale 7-load set in flight; vmcnt ordering at the
                // next step's WAIT7_TIE accounts for it (oldest retire first).
            }
            // halo hand-off (lanes 0-3) before the barrier
            if (lane == 0 && b > 0)           { s_hL[0] = __uint_as_float(bE.x);
                                                s_hL[1] = __uint_as_float(bE.y); }
            else if (lane == 1 && b > 0)      { s_hL[2] = __uint_as_float(bE.x); }
            else if (lane == 2 && b < NB - 1) { s_hR[0] = __uint_as_float(bE.x);
                                                s_hR[1] = __uint_as_float(bE.y); }
            else if (lane == 3 && b < NB - 1) { s_hR[2] = __uint_as_float(bE.x); }
            float m = fmaxf(fmaxf(fmaxf(__uint_as_float(b0), __uint_as_float(b1)),
                                  fmaxf(__uint_as_float(b2), __uint_as_float(b3))),
                            fmaxf(__uint_as_float(b4), __uint_as_float(b5)));
            m = wave_max64(m);
            if (lane == 63) s_smaxv = __int_as_float(__builtin_amdgcn_readlane(__float_as_int(m), 63));
        }
        BAR();   // the ONLY barrier per step: lgkmcnt fence + raw s_barrier (no vmcnt drain)
        if (s_panic) break;
        const float smax = s_smaxv;
        const float dt  = ((float)(0.9 * 0.001)) / smax;   // ref op order
        const float lam = dt / 0.001f;
        const float w   = lam * smax;

        // ===== per-wave edge fixes: lane 0 / lane 63 stencil terms from sE / remote halo =====
        if (lane == 0 && (wv > 0 || b > 0)) {
            float Al, Ql, Fl;
            if (wv > 0) { Al = sE[par][wv-1][1][0]; Ql = sE[par][wv-1][1][1]; Fl = sE[par][wv-1][1][2]; }
            else        { Al = s_hL[0];             Ql = s_hL[1];             Fl = s_hL[2]; }
            dFA[0]  = 0.5f * (Q[1] - Ql);
            lapA[0] = 0.5f * (A[1] - 2.0f * A[0] + Al);
            dFQ[0]  = 0.5f * (FQ[1] - Fl);
            lapQ[0] = 0.5f * (Q[1] - 2.0f * Q[0] + Ql);
        }
        if (lane == 63 && (wv < WPB - 1 || b < NB - 1)) {
            float Ar, Qr, Fr;
            if (wv < WPB - 1) { Ar = sE[par][wv+1][0][0]; Qr = sE[par][wv+1][0][1]; Fr = sE[par][wv+1][0][2]; }
            else              { Ar = s_hR[0];             Qr = s_hR[1];             Fr = s_hR[2]; }
            dFA[3]  = 0.5f * (Qr - Q[2]);
            lapA[3] = 0.5f * (Ar - 2.0f * A[3] + A[2]);
            dFQ[3]  = 0.5f * (Fr - FQ[2]);
            lapQ[3] = 0.5f * (Qr - 2.0f * Q[3] + Q[2]);
        }

        // ===== update + BCs + clamp =====
        #pragma unroll
        for (int c = 0; c < CPT; ++c) {
            int i = base + c;
            if (act[c] && i > 0 && i < MM - 1) {
                A[c] = fmaf(w, lapA[c], fmaf(-lam, dFA[c], A[c]));
                Q[c] = fmaf(w, lapQ[c], fmaf(-lam, dFQ[c], Q[c]));
            }
        }
        if (isStart) Q[0] = qFix;
        if (isEnd)   Q[3] = qFix;
        #pragma unroll
        for (int c = 0; c < CPT; ++c) A[c] = fmaxf(A[c], 1e-6f);

        // publish t+1 edge AQ ASAP (F follows after derived recompute)
        const int n4 = (t + 1) * 4;
        if (pubL) AG_STORE64(&g_edge_s[b][n4 + 0], packAQ(A[0], Q[0]));
        if (pubR) AG_STORE64(&g_edge_s[b][n4 + 2], packAQ(A[3], Q[3]));

        // ===== derived state for t+1: s4 path first (it gates every other block) =====
        float uu[CPT];
        s4 = 0.0f;
        #pragma unroll
        for (int c = 0; c < CPT; ++c) {
            sq[c] = sqrtf(A[c] / A0v[c]);
            uu[c] = Q[c] / A[c];
            float cc = sqrtf(cbv[c] * sq[c]);
            s4 = fmaxf(s4, act[c] ? (fabsf(uu[c]) + cc) : 0.0f);
        }
        {
            float red = wave_max64(s4);
            if (lane == 63) AG_STORE32(&g_wmax[gw][t + 1], __float_as_uint(red));  // per-wave direct publish
        }
        #pragma unroll
        for (int c = 0; c < CPT; ++c)
            FQ[c] = Q[c] * uu[c] + k2v[c] * A[c] * sq[c];

        if (pubL) AG_STORE64(&g_edge_s[b][n4 + 1], (unsigned long long)__float_as_uint(FQ[0]));
        if (pubR) AG_STORE64(&g_edge_s[b][n4 + 3], (unsigned long long)__float_as_uint(FQ[3]));

        // intra-block wave-edge state for t+1 (ordered vs readers by next step's BAR(),
        // which every wave reaches only after writing these)
        if (lane == 0)       { sE[npar][wv][0][0] = A[0]; sE[npar][wv][0][1] = Q[0]; sE[npar][wv][0][2] = FQ[0]; }
        else if (lane == 63) { sE[npar][wv][1][0] = A[3]; sE[npar][wv][1][1] = Q[3]; sE[npar][wv][1][2] = FQ[3]; }
    }
}

extern "C" void kernel_launch(void* const* d_in, const int* in_sizes, int n_in,
                              void* d_out, int out_size, void* d_ws, size_t ws_size,
                              hipStream_t stream) {
    (void)in_sizes; (void)n_in; (void)d_ws; (void)ws_size; (void)out_size;

    const float* Rs      = (const float*)d_in[0];
    const float* sim_dat = (const float*)d_in[1];
    const float* sdc     = (const float*)d_in[2];
    const float* inflow  = (const float*)d_in[3];
    float* out = (float*)d_out;

    hipLaunchKernelGGL(init_ws_kernel, dim3(240), dim3(256), 0, stream);

    // 88 blocks x 4 waves, ~1 KB LDS -> trivially co-resident on 256 CUs.
    hipLaunchKernelGGL(sim_kernel, dim3(NB), dim3(BS), 0, stream,
                       Rs, sim_dat, sdc, inflow, out);
}